// Round 18
// baseline (107.240 us; speedup 1.0000x reference)
//
#include <hip/hip_runtime.h>
#include <hip/hip_bf16.h>
#include <cmath>

// ---------- types ----------
typedef __attribute__((ext_vector_type(8))) short bf16x8;    // 8 bf16 (4 VGPRs) MFMA A/B frag
typedef __attribute__((ext_vector_type(4))) float f32x4;     // 16x16 C/D frag
typedef __attribute__((ext_vector_type(16))) float f32x16;   // 32x32 C/D frag

__device__ __forceinline__ unsigned short f2bf(float f) {
    union { float f; unsigned int i; } c; c.f = f;
    unsigned int i = c.i;
    unsigned int r = i + 0x7FFF + ((i >> 16) & 1);   // RTNE
    return (unsigned short)(r >> 16);
}

__device__ __forceinline__ float fast_exp2(float x) {   // D = 2^x (v_exp_f32; -inf -> 0)
    float r;
    asm("v_exp_f32 %0, %1" : "=v"(r) : "v"(x));
    return r;
}

// async global->LDS, 16B/lane. LDS dest: wave-uniform base (+lane*16 implicit); global src per-lane.
__device__ __forceinline__ void gload_lds16(const unsigned short* g, unsigned short* l) {
    __builtin_amdgcn_global_load_lds((const __attribute__((address_space(1))) unsigned int*)g,
                                     (__attribute__((address_space(3))) unsigned int*)l, 16, 0, 0);
}

// ---------- merged conversions: x, Wp, and Wq/Wk/Wv transpose ----------
__global__ void k_cvt_all(const float* __restrict__ x, const float* __restrict__ Wp,
                          const float* __restrict__ Wq, const float* __restrict__ Wk,
                          const float* __restrict__ Wv,
                          unsigned short* __restrict__ x_bf, unsigned short* __restrict__ Wp_bf,
                          unsigned short* __restrict__ Wt) {
    __shared__ unsigned short lt[64][72];
    int bid = blockIdx.x;
    int t = threadIdx.x;
    if (bid < 5120) {
        const float* src = (bid < 4096) ? x : Wp;
        unsigned short* dst = (bid < 4096) ? x_bf : Wp_bf;
        int i = ((bid < 4096) ? bid : (bid - 4096)) * 256 + t;
        float4 v = reinterpret_cast<const float4*>(src)[i];
        ushort4 o;
        o.x = f2bf(v.x); o.y = f2bf(v.y); o.z = f2bf(v.z); o.w = f2bf(v.w);
        reinterpret_cast<ushort4*>(dst)[i] = o;
        return;
    }
    int sub = bid - 5120;
    int ct  = sub & 15;
    int h   = (sub >> 4) & 15;
    int sec = sub >> 8;
    const float* W = (sec == 0) ? Wq : ((sec == 1) ? Wk : Wv);
    float sc = (sec == 0) ? 0.1803368801f : 1.0f;   // fold 1/sqrt(S)*log2e into Wq
    #pragma unroll
    for (int q = 0; q < 4; q++) {
        int id = t + q * 256;
        int c  = id >> 4;
        int s4 = (id & 15) * 4;
        float4 v = *reinterpret_cast<const float4*>(&W[((size_t)(h * 1024) + (ct * 64 + c)) * 64 + s4]);
        lt[s4 + 0][c] = f2bf(v.x * sc);
        lt[s4 + 1][c] = f2bf(v.y * sc);
        lt[s4 + 2][c] = f2bf(v.z * sc);
        lt[s4 + 3][c] = f2bf(v.w * sc);
    }
    __syncthreads();
    #pragma unroll
    for (int q = 0; q < 2; q++) {
        int id = t + q * 256;
        int s  = id >> 3;
        int c8 = (id & 7) * 8;
        bf16x8 val = *reinterpret_cast<const bf16x8*>(&lt[s][c8]);
        int n = sec * 1024 + h * 64 + s;
        *reinterpret_cast<bf16x8*>(&Wt[(size_t)n * 1024 + ct * 64 + c8]) = val;
    }
}

// ---------- merged QK + V GEMM: 768 blocks, BK=32, 3-BUFFER counted-vmcnt pipeline (R16) ----------
__launch_bounds__(256, 3)
__global__ void k_gemm_qkv(const unsigned short* __restrict__ x_bf,
                           const unsigned short* __restrict__ Wt,
                           unsigned short* __restrict__ q_nat,
                           unsigned short* __restrict__ k_nat,
                           unsigned short* __restrict__ vT) {
    __shared__ unsigned short Asm[3][128][32];   // 3 x 8 KB, 64B rows, granule-XOR swizzled
    __shared__ unsigned short Bsm[3][128][32];
    const int K = 1024;
    int cpx = gridDim.x >> 3;
    int bid = (blockIdx.x & 7) * cpx + (blockIdx.x >> 3);   // T1 bijective XCD remap (768%8==0)
    bool isV = (bid >= 512);
    const unsigned short* A;
    const unsigned short* Bt;
    int m0, n0;
    if (!isV) {
        n0 = (bid & 15) << 7;            // nb = 16 (N = 2048)
        m0 = (bid >> 4) << 7;            // M = 4096
        A = x_bf; Bt = Wt;
    } else {
        int vb = bid - 512;              // 0..255
        n0 = (vb & 31) << 7;             // nb = 32 (N = 4096)
        m0 = (vb >> 5) << 7;             // M = 1024
        A = Wt + (size_t)2048 * 1024;    // Wv^T rows
        Bt = x_bf;
    }
    int t = threadIdx.x;
    int lane = t & 63, w = t >> 6;
    int wr = w >> 1, wc = w & 1;
    int l15 = lane & 15, lg = lane >> 4;
    int srow = lane >> 2;                             // 0..15 row within 16-row chunk
    int scol = ((lane & 3) ^ ((lane >> 3) & 3)) << 3; // pre-swizzled source col (elems), rule #21

    f32x4 acc[4][4];
    #pragma unroll
    for (int i = 0; i < 4; i++)
        #pragma unroll
        for (int j = 0; j < 4; j++) acc[i][j] = (f32x4){0.f, 0.f, 0.f, 0.f};

    auto STAGE = [&](int kt, int buf) {   // 4 gload_lds per wave
        #pragma unroll
        for (int q = 0; q < 2; q++) {
            int rb = q * 64 + w * 16;                 // wave-uniform row base
            int row = rb + srow;
            gload_lds16(&A[(size_t)(m0 + row) * K + kt + scol], &Asm[buf][rb][0]);
            gload_lds16(&Bt[(size_t)(n0 + row) * K + kt + scol], &Bsm[buf][rb][0]);
        }
    };

    const int NT = K >> 5;               // 32 K-steps
    STAGE(0, 0);
    STAGE(32, 1);
    asm volatile("s_waitcnt vmcnt(4)" ::: "memory");   // tile 0 landed; tile 1 in flight
    __builtin_amdgcn_s_barrier();
    int cur = 0;

    for (int tt = 0; tt < NT; tt++) {
        bool more = (tt + 2 < NT);
        if (more) {
            int sbuf = cur + 2; if (sbuf >= 3) sbuf -= 3;
            STAGE((tt + 2) << 5, sbuf);  // flies over this iteration's compute AND the barrier
        }

        bf16x8 af[4], bfr[4];
        int xg = (l15 >> 1) & 3;         // read-side granule XOR
        #pragma unroll
        for (int mi = 0; mi < 4; mi++) {
            int row = wr * 64 + mi * 16 + l15;
            af[mi] = *reinterpret_cast<const bf16x8*>((const char*)&Asm[cur][row][0] + ((lg ^ xg) << 4));
        }
        #pragma unroll
        for (int nj = 0; nj < 4; nj++) {
            int row = wc * 64 + nj * 16 + l15;
            bfr[nj] = *reinterpret_cast<const bf16x8*>((const char*)&Bsm[cur][row][0] + ((lg ^ xg) << 4));
        }
        asm volatile("s_waitcnt lgkmcnt(0)" ::: "memory");
        __builtin_amdgcn_sched_barrier(0);            // rule #18
        __builtin_amdgcn_s_setprio(1);
        #pragma unroll
        for (int mi = 0; mi < 4; mi++)
            #pragma unroll
            for (int nj = 0; nj < 4; nj++)
                acc[mi][nj] = __builtin_amdgcn_mfma_f32_16x16x32_bf16(af[mi], bfr[nj], acc[mi][nj], 0, 0, 0);
        __builtin_amdgcn_s_setprio(0);

        if (more) {
            asm volatile("s_waitcnt vmcnt(4)" ::: "memory");   // tile tt+1 landed; tt+2 in flight
        } else {
            asm volatile("s_waitcnt vmcnt(0)" ::: "memory");   // tail drain
        }
        __builtin_amdgcn_s_barrier();
        cur = (cur == 2) ? 0 : cur + 1;
    }

    unsigned short* qkdst = nullptr;
    int noff = 0;
    if (!isV) { qkdst = (n0 < 1024) ? q_nat : k_nat; noff = (n0 < 1024) ? 0 : 1024; }
    #pragma unroll
    for (int mi = 0; mi < 4; mi++) {
        #pragma unroll
        for (int nj = 0; nj < 4; nj++) {
            #pragma unroll
            for (int r = 0; r < 4; r++) {
                int m = m0 + wr * 64 + mi * 16 + lg * 4 + r;
                int n = n0 + wc * 64 + nj * 16 + l15;
                float v = acc[mi][nj][r];
                if (!isV) {
                    qkdst[(size_t)m * 1024 + (n - noff)] = f2bf(v);
                } else {
                    int bb = n >> 11, ttn = n & 2047;
                    int hh = m >> 6, ss = m & 63;
                    vT[(((size_t)(bb * 16 + hh)) * 64 + ss) * 2048 + ttn] = f2bf(v);
                }
            }
        }
    }
}

// ---------- flash attention: QBLK=128, KVBLK=128, ALL-WARPS-COMPUTE kv-half split ----------
// grid = 512 blocks, anti-correlated pairing. kv-128 tiles jt=0..p, double-buffered.
// Phase k: ALL warps stage tile k+1 (issue-only; lands under compute) then ALL warps compute
// tile k — warp-group pr takes kv-half pr (disjoint kv partition -> plain-add merge unchanged).
// FIXED-SHIFT softmax (m=0, scores bounded ~|7|); ell via MFMA ones-fragment.
__launch_bounds__(512, 2)
__global__ void k_attn(const unsigned short* __restrict__ q_nat,
                       const unsigned short* __restrict__ k_nat,
                       const unsigned short* __restrict__ vT,
                       unsigned short* __restrict__ y_bf) {
    __shared__ __align__(16) unsigned short SM[2][2][128][64];  // [buf][K/V][row(half*64+r)][col]
    __shared__ float clB[128];                                  // stream-B row sums
    const int T = 2048, H = 16;
    int bid = blockIdx.x;
    int bh = bid & 31;
    int g  = bid >> 5;                   // 0..15
    int p  = (g < 8) ? (15 - g) : (g - 8);   // anti-correlated long/short pairing
    int h = bh & 15, b = bh >> 4;
    int t = threadIdx.x;
    int lane = t & 63, w = t >> 6;       // 8 warps
    int pr = w >> 2, rg = w & 3;         // pr = kv-half, rg = q-row-group (0..3)
    int l31 = lane & 31, hi = lane >> 5;
    int q0 = p << 7;
    int warp_q0 = q0 + rg * 32;
    int qg = warp_q0 + l31;              // this lane's q-row

    const unsigned short* kbase = k_nat + (size_t)(b * T) * 1024 + h * 64;
    const unsigned short* vbase = vT + ((size_t)(b * H + h) * 64) * 2048;

    int sxor = ((lane & 7) ^ (lane >> 3)) << 3;   // pre-swizzled source col (elems)

    // all-warp cooperative stage of one kv-128 tile (K 16KB + V 16KB); 4 issues/thread
    auto STAGE = [&](int jt, int buf) {
        #pragma unroll
        for (int q = 0; q < 2; q++) {
            int rb = w * 16 + q * 8;              // wave-uniform row base 0..127
            int grow = rb + (lane >> 3);
            gload_lds16(kbase + (size_t)(jt * 128 + grow) * 1024 + sxor,
                        (unsigned short*)&SM[buf][0][0][0] + rb * 64);
            gload_lds16(vbase + (size_t)(grow & 63) * 2048 + jt * 128 + (grow >> 6) * 64 + sxor,
                        (unsigned short*)&SM[buf][1][0][0] + rb * 64);
        }
    };

    // Q fragments (B operand): lane holds Q[q=qg][k = tt*16 + hi*8 + 0..7] (exp2-prescaled)
    bf16x8 qf[4];
    #pragma unroll
    for (int tt = 0; tt < 4; tt++)
        qf[tt] = *reinterpret_cast<const bf16x8*>(
            q_nat + (size_t)(b * T + qg) * 1024 + h * 64 + tt * 16 + hi * 8);

    bf16x8 ones;
    #pragma unroll
    for (int z = 0; z < 8; z++) ones[z] = (short)0x3F80;

    f32x16 acc0, acc1, lacc;
    #pragma unroll
    for (int r = 0; r < 16; r++) { acc0[r] = 0.f; acc1[r] = 0.f; lacc[r] = 0.f; }

    STAGE(0, 0);
    __syncthreads();
    int buf = 0;

    for (int k = 0; k <= p; k++) {
        if (k < p) STAGE(k + 1, buf ^ 1);       // issue early; lands under the compute below

        const char* kb = (const char*)&SM[buf][0][pr * 64][0];
        const char* vb = (const char*)&SM[buf][1][pr * 64][0];
        int rsw = (l31 & 7) << 4;               // read-side XOR
        int j64 = 2 * k + pr;                   // this warp's kv-64 index

        // S^T = K · Q^T
        f32x16 s0, s1;
        #pragma unroll
        for (int r = 0; r < 16; r++) { s0[r] = 0.f; s1[r] = 0.f; }
        __builtin_amdgcn_s_setprio(1);
        #pragma unroll
        for (int tt = 0; tt < 4; tt++) {
            int cb = (tt * 32 + hi * 16) ^ rsw;
            bf16x8 kf0 = *reinterpret_cast<const bf16x8*>(kb + l31 * 128 + cb);
            bf16x8 kf1 = *reinterpret_cast<const bf16x8*>(kb + (32 + l31) * 128 + cb);
            s0 = __builtin_amdgcn_mfma_f32_32x32x16_bf16(kf0, qf[tt], s0, 0, 0, 0);
            s1 = __builtin_amdgcn_mfma_f32_32x32x16_bf16(kf1, qf[tt], s1, 0, 0, 0);
        }
        __builtin_amdgcn_s_setprio(0);

        // causal mask; exp2(-inf) = 0
        if (j64 * 64 + 63 > warp_q0) {
            #pragma unroll
            for (int r = 0; r < 16; r++) {
                int kvr = (r & 3) + 8 * (r >> 2) + 4 * hi + j64 * 64;
                if (kvr > qg) s0[r] = -INFINITY;
                if (kvr + 32 > qg) s1[r] = -INFINITY;
            }
        }

        // P = 2^S (fixed shift m=0)
        #pragma unroll
        for (int r = 0; r < 16; r++) {
            s0[r] = fast_exp2(s0[r]);
            s1[r] = fast_exp2(s1[r]);
        }

        // pack P to bf16 pairs
        unsigned int c[16];
        #pragma unroll
        for (int i2 = 0; i2 < 8; i2++) {
            asm("v_cvt_pk_bf16_f32 %0, %1, %2" : "=v"(c[i2]) : "v"(s0[2 * i2]), "v"(s0[2 * i2 + 1]));
            asm("v_cvt_pk_bf16_f32 %0, %1, %2" : "=v"(c[8 + i2]) : "v"(s1[2 * i2]), "v"(s1[2 * i2 + 1]));
        }
        // assemble PV A-frags via lane^32 exchange
        bf16x8 pa[4];
        #pragma unroll
        for (int ks = 0; ks < 4; ks++) {
            unsigned int clo0 = c[ks * 4 + 0], clo1 = c[ks * 4 + 1];
            unsigned int chi0 = c[ks * 4 + 2], chi1 = c[ks * 4 + 3];
            unsigned int pl0 = (unsigned int)__shfl_xor((int)clo0, 32, 64);
            unsigned int pl1 = (unsigned int)__shfl_xor((int)clo1, 32, 64);
            unsigned int ph0 = (unsigned int)__shfl_xor((int)chi0, 32, 64);
            unsigned int ph1 = (unsigned int)__shfl_xor((int)chi1, 32, 64);
            union { unsigned int u[4]; bf16x8 v; } fr;
            fr.u[0] = hi ? ph0 : clo0;
            fr.u[1] = hi ? ph1 : clo1;
            fr.u[2] = hi ? chi0 : pl0;
            fr.u[3] = hi ? chi1 : pl1;
            pa[ks] = fr.v;
        }

        // O += P·V ; ell += P·1
        __builtin_amdgcn_s_setprio(1);
        #pragma unroll
        for (int ks = 0; ks < 4; ks++) {
            int cb = (ks * 32 + hi * 16) ^ rsw;
            bf16x8 v0 = *reinterpret_cast<const bf16x8*>(vb + l31 * 128 + cb);
            bf16x8 v1 = *reinterpret_cast<const bf16x8*>(vb + (32 + l31) * 128 + cb);
            acc0 = __builtin_amdgcn_mfma_f32_32x32x16_bf16(pa[ks], v0, acc0, 0, 0, 0);
            acc1 = __builtin_amdgcn_mfma_f32_32x32x16_bf16(pa[ks], v1, acc1, 0, 0, 0);
            lacc = __builtin_amdgcn_mfma_f32_32x32x16_bf16(pa[ks], ones, lacc, 0, 0, 0);
        }
        __builtin_amdgcn_s_setprio(0);

        __syncthreads();               // staged loads drained (cheap: issued a phase ago) + handoff
        buf ^= 1;
    }

    // ---- cross-half merge: O = O_A + O_B, ell = ellA + ellB (disjoint kv -> plain add) ----
    float* Ocomb = (float*)&SM[0][0][0][0];   // 128 x 64 f32 = 32 KB (reuse staging LDS)
    if (pr == 1) {
        #pragma unroll
        for (int r = 0; r < 16; r++) {
            int qr = (r & 3) + 8 * (r >> 2) + 4 * hi;
            int rr = rg * 32 + qr;
            Ocomb[rr * 64 + l31] = acc0[r];
            Ocomb[rr * 64 + 32 + l31] = acc1[r];
            if (l31 == 0) clB[rr] = lacc[r];
        }
    }
    __syncthreads();
    if (pr == 0) {
        #pragma unroll
        for (int r = 0; r < 16; r++) {
            int qr = (r & 3) + 8 * (r >> 2) + 4 * hi;
            int rr = rg * 32 + qr;
            float lt2 = lacc[r] + clB[rr];
            float dv = 1.0f / lt2;
            float o0 = acc0[r] + Ocomb[rr * 64 + l31];
            float o1 = acc1[r] + Ocomb[rr * 64 + 32 + l31];
            size_t row = (size_t)(b * T + q0 + rr) * 1024 + h * 64;
            y_bf[row + l31] = f2bf(o0 * dv);
            y_bf[row + 32 + l31] = f2bf(o1 * dv);
        }
    }
}

// ---------- projection GEMM: 128x64 tiles -> 512 blocks (2 blocks/CU), BK=64 2-phase ----------
__launch_bounds__(256, 2)
__global__ void k_gemm_proj(const unsigned short* __restrict__ A,
                            const unsigned short* __restrict__ Bt,
                            float* __restrict__ out, const float* __restrict__ bp) {
    __shared__ unsigned short Asm[2][128][64];   // 2 x 16 KB
    __shared__ unsigned short Bsm[2][64][64];    // 2 x 8 KB
    const int K = 1024, nb = 16;         // M=4096 (32 m-tiles), N=1024 (16 n-tiles)
    int cpx = gridDim.x >> 3;
    int bid = (blockIdx.x & 7) * cpx + (blockIdx.x >> 3);   // T1 remap (512%8==0)
    int n0 = (bid % nb) << 6;            // 64-wide n tiles
    int m0 = (bid / nb) << 7;            // 128-tall m tiles
    int t = threadIdx.x;
    int lane = t & 63, w = t >> 6;
    int wr = w >> 1, wc = w & 1;
    int l15 = lane & 15, lg = lane >> 4;
    int sr = lane >> 3;
    int scol = ((lane & 7) ^ sr) << 3;

    f32x4 acc[4][2];
    #pragma unroll
    for (int i = 0; i < 4; i++)
        #pragma unroll
        for (int j = 0; j < 2; j++) acc[i][j] = (f32x4){0.f, 0.f, 0.f, 0.f};

    auto STAGE = [&](int kt, int buf) {
        #pragma unroll
        for (int q = 0; q < 4; q++) {
            int rb = q * 32 + w * 8;
            gload_lds16(&A[(size_t)(m0 + rb + sr) * K + kt + scol], &Asm[buf][rb][0]);
        }
        #pragma unroll
        for (int q = 0; q < 2; q++) {
            int rb = q * 32 + w * 8;
            gload_lds16(&Bt[(size_t)(n0 + rb + sr) * K + kt + scol], &Bsm[buf][rb][0]);
        }
    };

    const int NT = K >> 6;
    STAGE(0, 0);
    asm volatile("s_waitcnt vmcnt(0)" ::: "memory");
    __builtin_amdgcn_s_barrier();
    int cur = 0;

    for (int tt = 0; tt < NT; tt++) {
        if (tt + 1 < NT) STAGE((tt + 1) << 6, cur ^ 1);
        bf16x8 af[4][2], bfr[2][2];
        int x15 = (l15 & 7) << 3;
        #pragma unroll
        for (int mi = 0; mi < 4; mi++) {
            int row = wr * 64 + mi * 16 + l15;
            af[mi][0] = *reinterpret_cast<const bf16x8*>(&Asm[cur][row][(lg * 8) ^ x15]);
            af[mi][1] = *reinterpret_cast<const bf16x8*>(&Asm[cur][row][(32 + lg * 8) ^ x15]);
        }
        #pragma unroll
        for (int nj = 0; nj < 2; nj++) {
            int row = wc * 32 + nj * 16 + l15;
            bfr[nj][0] = *reinterpret_cast<const bf16x8*>(&Bsm[cur][row][(lg * 8) ^ x15]);
            bfr[nj][1] = *reinterpret_cast<const bf16x8*>(&Bsm[cur][row][(32 + lg * 8) ^ x15]);
        }
        asm volatile("s_waitcnt lgkmcnt(0)" ::: "memory");
        __builtin_amdgcn_sched_barrier(0);
        __builtin_amdgcn_s_setprio(1);
        #pragma unroll
        for (int mi = 0; mi < 4; mi++)
            #pragma unroll
            for (int nj = 0; nj < 2; nj++) {
                acc[mi][nj] = __builtin_amdgcn_mfma_f32_16x16x32_bf16(af[mi][0], bfr[nj][0], acc[mi][nj], 0, 0, 0);
                acc[mi][nj] = __builtin_amdgcn_mfma_f32_16x16x32_bf16(af[mi][1], bfr[nj][1], acc[mi][nj], 0, 0, 0);
            }
        __builtin_amdgcn_s_setprio(0);
        asm volatile("s_waitcnt vmcnt(0)" ::: "memory");
        __builtin_amdgcn_s_barrier();
        cur ^= 1;
    }

    #pragma unroll
    for (int mi = 0; mi < 4; mi++)
        #pragma unroll
        for (int nj = 0; nj < 2; nj++)
            #pragma unroll
            for (int r = 0; r < 4; r++) {
                int m = m0 + wr * 64 + mi * 16 + lg * 4 + r;
                int n = n0 + wc * 32 + nj * 16 + l15;
                out[(size_t)m * 1024 + n] = acc[mi][nj][r] + bp[n];
            }
}

// ---------- launch ----------
extern "C" void kernel_launch(void* const* d_in, const int* in_sizes, int n_in,
                              void* d_out, int out_size, void* d_ws, size_t ws_size,
                              hipStream_t stream) {
    const float* x  = (const float*)d_in[0];
    const float* Wq = (const float*)d_in[1];
    const float* Wk = (const float*)d_in[2];
    const float* Wv = (const float*)d_in[3];
    const float* Wp = (const float*)d_in[4];
    const float* bp = (const float*)d_in[5];
    float* out = (float*)d_out;

    char* ws = (char*)d_ws;
    unsigned short* x_bf  = (unsigned short*)(ws);                           // 8 MB
    unsigned short* Wt    = (unsigned short*)(ws + ((size_t)8  << 20));      // 6 MB
    unsigned short* Wp_bf = (unsigned short*)(ws + ((size_t)14 << 20));      // 2 MB
    unsigned short* q_nat = (unsigned short*)(ws + ((size_t)16 << 20));      // 8 MB
    unsigned short* k_nat = (unsigned short*)(ws + ((size_t)24 << 20));      // 8 MB
    unsigned short* vT    = (unsigned short*)(ws + ((size_t)32 << 20));      // 8 MB
    unsigned short* y_bf  = (unsigned short*)(ws + ((size_t)40 << 20));      // 8 MB

    k_cvt_all<<<5888, 256, 0, stream>>>(x, Wp, Wq, Wk, Wv, x_bf, Wp_bf, Wt);
    k_gemm_qkv<<<768, 256, 0, stream>>>(x_bf, Wt, q_nat, k_nat, vT);
    k_attn<<<512, 512, 0, stream>>>(q_nat, k_nat, vT, y_bf);
    k_gemm_proj<<<512, 256, 0, stream>>>(y_bf, Wp_bf, out, bp);
}

// Round 19
// 99.863 us; speedup vs baseline: 1.0739x; 1.0739x over previous
//
#include <hip/hip_runtime.h>
#include <hip/hip_bf16.h>
#include <cmath>

// ---------- types ----------
typedef __attribute__((ext_vector_type(8))) short bf16x8;    // 8 bf16 (4 VGPRs) MFMA A/B frag
typedef __attribute__((ext_vector_type(4))) float f32x4;     // 16x16 C/D frag
typedef __attribute__((ext_vector_type(16))) float f32x16;   // 32x32 C/D frag

__device__ __forceinline__ unsigned short f2bf(float f) {
    union { float f; unsigned int i; } c; c.f = f;
    unsigned int i = c.i;
    unsigned int r = i + 0x7FFF + ((i >> 16) & 1);   // RTNE
    return (unsigned short)(r >> 16);
}

__device__ __forceinline__ float fast_exp2(float x) {   // D = 2^x (v_exp_f32; -inf -> 0)
    float r;
    asm("v_exp_f32 %0, %1" : "=v"(r) : "v"(x));
    return r;
}

// async global->LDS, 16B/lane. LDS dest: wave-uniform base (+lane*16 implicit); global src per-lane.
__device__ __forceinline__ void gload_lds16(const unsigned short* g, unsigned short* l) {
    __builtin_amdgcn_global_load_lds((const __attribute__((address_space(1))) unsigned int*)g,
                                     (__attribute__((address_space(3))) unsigned int*)l, 16, 0, 0);
}

// ---------- merged conversions: x, Wp, and Wq/Wk/Wv transpose ----------
__global__ void k_cvt_all(const float* __restrict__ x, const float* __restrict__ Wp,
                          const float* __restrict__ Wq, const float* __restrict__ Wk,
                          const float* __restrict__ Wv,
                          unsigned short* __restrict__ x_bf, unsigned short* __restrict__ Wp_bf,
                          unsigned short* __restrict__ Wt) {
    __shared__ unsigned short lt[64][72];
    int bid = blockIdx.x;
    int t = threadIdx.x;
    if (bid < 5120) {
        const float* src = (bid < 4096) ? x : Wp;
        unsigned short* dst = (bid < 4096) ? x_bf : Wp_bf;
        int i = ((bid < 4096) ? bid : (bid - 4096)) * 256 + t;
        float4 v = reinterpret_cast<const float4*>(src)[i];
        ushort4 o;
        o.x = f2bf(v.x); o.y = f2bf(v.y); o.z = f2bf(v.z); o.w = f2bf(v.w);
        reinterpret_cast<ushort4*>(dst)[i] = o;
        return;
    }
    int sub = bid - 5120;
    int ct  = sub & 15;
    int h   = (sub >> 4) & 15;
    int sec = sub >> 8;
    const float* W = (sec == 0) ? Wq : ((sec == 1) ? Wk : Wv);
    float sc = (sec == 0) ? 0.1803368801f : 1.0f;   // fold 1/sqrt(S)*log2e into Wq
    #pragma unroll
    for (int q = 0; q < 4; q++) {
        int id = t + q * 256;
        int c  = id >> 4;
        int s4 = (id & 15) * 4;
        float4 v = *reinterpret_cast<const float4*>(&W[((size_t)(h * 1024) + (ct * 64 + c)) * 64 + s4]);
        lt[s4 + 0][c] = f2bf(v.x * sc);
        lt[s4 + 1][c] = f2bf(v.y * sc);
        lt[s4 + 2][c] = f2bf(v.z * sc);
        lt[s4 + 3][c] = f2bf(v.w * sc);
    }
    __syncthreads();
    #pragma unroll
    for (int q = 0; q < 2; q++) {
        int id = t + q * 256;
        int s  = id >> 3;
        int c8 = (id & 7) * 8;
        bf16x8 val = *reinterpret_cast<const bf16x8*>(&lt[s][c8]);
        int n = sec * 1024 + h * 64 + s;
        *reinterpret_cast<bf16x8*>(&Wt[(size_t)n * 1024 + ct * 64 + c8]) = val;
    }
}

// ---------- merged QK + V GEMM: 768 blocks, BK=32 double-buffer in 32 KB (4 blocks/CU) ----------
// QK: C = x_bf[4096x1024] * Wt[0:2048]^T -> q_nat / k_nat.
// V : C = WvT[1024x1024] * x_bf^T -> vT[(b*16+h)*64+s][t] (coalesced over t).
__launch_bounds__(256, 4)
__global__ void k_gemm_qkv(const unsigned short* __restrict__ x_bf,
                           const unsigned short* __restrict__ Wt,
                           unsigned short* __restrict__ q_nat,
                           unsigned short* __restrict__ k_nat,
                           unsigned short* __restrict__ vT) {
    __shared__ unsigned short Asm[2][128][32];   // 2 x 8 KB, 64B rows, granule-XOR swizzled
    __shared__ unsigned short Bsm[2][128][32];
    const int K = 1024;
    int cpx = gridDim.x >> 3;
    int bid = (blockIdx.x & 7) * cpx + (blockIdx.x >> 3);   // T1 bijective XCD remap (768%8==0)
    bool isV = (bid >= 512);
    const unsigned short* A;
    const unsigned short* Bt;
    int m0, n0;
    if (!isV) {
        n0 = (bid & 15) << 7;            // nb = 16 (N = 2048)
        m0 = (bid >> 4) << 7;            // M = 4096
        A = x_bf; Bt = Wt;
    } else {
        int vb = bid - 512;              // 0..255
        n0 = (vb & 31) << 7;             // nb = 32 (N = 4096)
        m0 = (vb >> 5) << 7;             // M = 1024
        A = Wt + (size_t)2048 * 1024;    // Wv^T rows
        Bt = x_bf;
    }
    int t = threadIdx.x;
    int lane = t & 63, w = t >> 6;
    int wr = w >> 1, wc = w & 1;
    int l15 = lane & 15, lg = lane >> 4;
    int srow = lane >> 2;                             // 0..15 row within 16-row chunk
    int scol = ((lane & 3) ^ ((lane >> 3) & 3)) << 3; // pre-swizzled source col (elems), rule #21

    f32x4 acc[4][4];
    #pragma unroll
    for (int i = 0; i < 4; i++)
        #pragma unroll
        for (int j = 0; j < 4; j++) acc[i][j] = (f32x4){0.f, 0.f, 0.f, 0.f};

    auto STAGE = [&](int kt, int buf) {
        #pragma unroll
        for (int q = 0; q < 2; q++) {
            int rb = q * 64 + w * 16;                 // wave-uniform row base
            int row = rb + srow;
            gload_lds16(&A[(size_t)(m0 + row) * K + kt + scol], &Asm[buf][rb][0]);
            gload_lds16(&Bt[(size_t)(n0 + row) * K + kt + scol], &Bsm[buf][rb][0]);
        }
    };

    const int NT = K >> 5;               // 32 K-steps
    STAGE(0, 0);
    asm volatile("s_waitcnt vmcnt(0)" ::: "memory");
    __builtin_amdgcn_s_barrier();
    int cur = 0;

    for (int tt = 0; tt < NT; tt++) {
        if (tt + 1 < NT) STAGE((tt + 1) << 5, cur ^ 1);   // next-tile loads fly over compute

        bf16x8 af[4], bfr[4];
        int xg = (l15 >> 1) & 3;         // read-side granule XOR
        #pragma unroll
        for (int mi = 0; mi < 4; mi++) {
            int row = wr * 64 + mi * 16 + l15;
            af[mi] = *reinterpret_cast<const bf16x8*>((const char*)&Asm[cur][row][0] + ((lg ^ xg) << 4));
        }
        #pragma unroll
        for (int nj = 0; nj < 4; nj++) {
            int row = wc * 64 + nj * 16 + l15;
            bfr[nj] = *reinterpret_cast<const bf16x8*>((const char*)&Bsm[cur][row][0] + ((lg ^ xg) << 4));
        }
        asm volatile("s_waitcnt lgkmcnt(0)" ::: "memory");
        __builtin_amdgcn_sched_barrier(0);            // rule #18
        __builtin_amdgcn_s_setprio(1);
        #pragma unroll
        for (int mi = 0; mi < 4; mi++)
            #pragma unroll
            for (int nj = 0; nj < 4; nj++)
                acc[mi][nj] = __builtin_amdgcn_mfma_f32_16x16x32_bf16(af[mi], bfr[nj], acc[mi][nj], 0, 0, 0);
        __builtin_amdgcn_s_setprio(0);

        asm volatile("s_waitcnt vmcnt(0)" ::: "memory");
        __builtin_amdgcn_s_barrier();
        cur ^= 1;
    }

    unsigned short* qkdst = nullptr;
    int noff = 0;
    if (!isV) { qkdst = (n0 < 1024) ? q_nat : k_nat; noff = (n0 < 1024) ? 0 : 1024; }
    #pragma unroll
    for (int mi = 0; mi < 4; mi++) {
        #pragma unroll
        for (int nj = 0; nj < 4; nj++) {
            #pragma unroll
            for (int r = 0; r < 4; r++) {
                int m = m0 + wr * 64 + mi * 16 + lg * 4 + r;
                int n = n0 + wc * 64 + nj * 16 + l15;
                float v = acc[mi][nj][r];
                if (!isV) {
                    qkdst[(size_t)m * 1024 + (n - noff)] = f2bf(v);
                } else {
                    int bb = n >> 11, ttn = n & 2047;
                    int hh = m >> 6, ss = m & 63;
                    vT[(((size_t)(bb * 16 + hh)) * 64 + ss) * 2048 + ttn] = f2bf(v);
                }
            }
        }
    }
}

// ---------- flash attention: QBLK=128, 8 warps, PHASE-SHIFTED KV streams (best measured: 40.0 us) ----------
// grid = 512 blocks, anti-correlated pairing (g<8 ? 15-g : g-8).
// Phase k (k=0..2p+1): stream (k&1) COMPUTES tile k; the other stream STAGES tile k+1.
// The stager's vmcnt drain overlaps the computing stream's MFMA/VALU -> staging latency hidden.
// FIXED-SHIFT softmax (m=0, scores bounded ~|7|); ell via MFMA ones-fragment. Merge = add.
__launch_bounds__(512, 4)
__global__ void k_attn(const unsigned short* __restrict__ q_nat,
                       const unsigned short* __restrict__ k_nat,
                       const unsigned short* __restrict__ vT,
                       unsigned short* __restrict__ y_bf) {
    __shared__ __align__(16) unsigned short SM[2][2][64][64];   // [K/V][stream][row][col], XOR-swizzled
    __shared__ float clB[128];                                  // stream-B row sums
    const int T = 2048, H = 16;
    int bid = blockIdx.x;
    int bh = bid & 31;
    int g  = bid >> 5;                   // 0..15
    int p  = (g < 8) ? (15 - g) : (g - 8);   // anti-correlated long/short pairing
    int h = bh & 15, b = bh >> 4;
    int t = threadIdx.x;
    int lane = t & 63, w = t >> 6;       // 8 warps
    int pr = w >> 2, rg = w & 3;         // pr = stream, rg = row-group (0..3)
    int l31 = lane & 31, hi = lane >> 5;
    int q0 = p << 7;
    int warp_q0 = q0 + rg * 32;
    int qg = warp_q0 + l31;              // this lane's q-row
    int jmax = 2 * p + 1;                // tiles 0..jmax; stream pr owns tiles with (j&1)==pr

    const unsigned short* kbase = k_nat + (size_t)(b * T) * 1024 + h * 64;
    const unsigned short* vbase = vT + ((size_t)(b * H + h) * 64) * 2048;

    int sxor = ((lane & 7) ^ (lane >> 3)) << 3;   // pre-swizzled source col (elems)

    auto STAGE = [&](int j) {
        #pragma unroll
        for (int r = 0; r < 2; r++) {
            int rb = r * 32 + rg * 8;             // wave-uniform row base
            int grow = rb + (lane >> 3);
            gload_lds16(kbase + (size_t)(j * 64 + grow) * 1024 + sxor, &SM[0][pr][rb][0]);
            gload_lds16(vbase + (size_t)grow * 2048 + j * 64 + sxor, &SM[1][pr][rb][0]);
        }
    };

    // Q fragments (B operand): lane holds Q[q=qg][k = tt*16 + hi*8 + 0..7] (exp2-prescaled)
    bf16x8 qf[4];
    #pragma unroll
    for (int tt = 0; tt < 4; tt++)
        qf[tt] = *reinterpret_cast<const bf16x8*>(
            q_nat + (size_t)(b * T + qg) * 1024 + h * 64 + tt * 16 + hi * 8);

    bf16x8 ones;
    #pragma unroll
    for (int z = 0; z < 8; z++) ones[z] = (short)0x3F80;

    f32x16 acc0, acc1, lacc;
    #pragma unroll
    for (int r = 0; r < 16; r++) { acc0[r] = 0.f; acc1[r] = 0.f; lacc[r] = 0.f; }

    if (pr == 0) STAGE(0);               // prologue: stream A stages tile 0
    __syncthreads();

    for (int k = 0; k <= jmax; k++) {
        bool iCompute = (pr == (k & 1));
        if (!iCompute) {
            if (k + 1 <= jmax) STAGE(k + 1);   // stage my next tile; drain overlaps their compute
        } else {
            const char* kb = (const char*)&SM[0][pr][0][0];
            const char* vb = (const char*)&SM[1][pr][0][0];
            int rsw = (l31 & 7) << 4;    // read-side XOR
            int j = k;

            // S^T = K · Q^T
            f32x16 s0, s1;
            #pragma unroll
            for (int r = 0; r < 16; r++) { s0[r] = 0.f; s1[r] = 0.f; }
            __builtin_amdgcn_s_setprio(1);
            #pragma unroll
            for (int tt = 0; tt < 4; tt++) {
                int cb = (tt * 32 + hi * 16) ^ rsw;
                bf16x8 kf0 = *reinterpret_cast<const bf16x8*>(kb + l31 * 128 + cb);
                bf16x8 kf1 = *reinterpret_cast<const bf16x8*>(kb + (32 + l31) * 128 + cb);
                s0 = __builtin_amdgcn_mfma_f32_32x32x16_bf16(kf0, qf[tt], s0, 0, 0, 0);
                s1 = __builtin_amdgcn_mfma_f32_32x32x16_bf16(kf1, qf[tt], s1, 0, 0, 0);
            }
            __builtin_amdgcn_s_setprio(0);

            // causal mask; exp2(-inf) = 0
            if (j * 64 + 63 > warp_q0) {
                #pragma unroll
                for (int r = 0; r < 16; r++) {
                    int kvr = (r & 3) + 8 * (r >> 2) + 4 * hi + j * 64;
                    if (kvr > qg) s0[r] = -INFINITY;
                    if (kvr + 32 > qg) s1[r] = -INFINITY;
                }
            }

            // P = 2^S (fixed shift m=0)
            #pragma unroll
            for (int r = 0; r < 16; r++) {
                s0[r] = fast_exp2(s0[r]);
                s1[r] = fast_exp2(s1[r]);
            }

            // pack P to bf16 pairs
            unsigned int c[16];
            #pragma unroll
            for (int i2 = 0; i2 < 8; i2++) {
                asm("v_cvt_pk_bf16_f32 %0, %1, %2" : "=v"(c[i2]) : "v"(s0[2 * i2]), "v"(s0[2 * i2 + 1]));
                asm("v_cvt_pk_bf16_f32 %0, %1, %2" : "=v"(c[8 + i2]) : "v"(s1[2 * i2]), "v"(s1[2 * i2 + 1]));
            }
            // assemble PV A-frags via lane^32 exchange
            bf16x8 pa[4];
            #pragma unroll
            for (int ks = 0; ks < 4; ks++) {
                unsigned int clo0 = c[ks * 4 + 0], clo1 = c[ks * 4 + 1];
                unsigned int chi0 = c[ks * 4 + 2], chi1 = c[ks * 4 + 3];
                unsigned int pl0 = (unsigned int)__shfl_xor((int)clo0, 32, 64);
                unsigned int pl1 = (unsigned int)__shfl_xor((int)clo1, 32, 64);
                unsigned int ph0 = (unsigned int)__shfl_xor((int)chi0, 32, 64);
                unsigned int ph1 = (unsigned int)__shfl_xor((int)chi1, 32, 64);
                union { unsigned int u[4]; bf16x8 v; } fr;
                fr.u[0] = hi ? ph0 : clo0;
                fr.u[1] = hi ? ph1 : clo1;
                fr.u[2] = hi ? chi0 : pl0;
                fr.u[3] = hi ? chi1 : pl1;
                pa[ks] = fr.v;
            }

            // O += P·V ; ell += P·1
            __builtin_amdgcn_s_setprio(1);
            #pragma unroll
            for (int ks = 0; ks < 4; ks++) {
                int cb = (ks * 32 + hi * 16) ^ rsw;
                bf16x8 v0 = *reinterpret_cast<const bf16x8*>(vb + l31 * 128 + cb);
                bf16x8 v1 = *reinterpret_cast<const bf16x8*>(vb + (32 + l31) * 128 + cb);
                acc0 = __builtin_amdgcn_mfma_f32_32x32x16_bf16(pa[ks], v0, acc0, 0, 0, 0);
                acc1 = __builtin_amdgcn_mfma_f32_32x32x16_bf16(pa[ks], v1, acc1, 0, 0, 0);
                lacc = __builtin_amdgcn_mfma_f32_32x32x16_bf16(pa[ks], ones, lacc, 0, 0, 0);
            }
            __builtin_amdgcn_s_setprio(0);
        }

        __syncthreads();                 // phase boundary (stager drained; computer done reading)
    }

    // ---- cross-stream merge: O = O_A + O_B, ell = ellA + ellB (fixed shift -> plain add) ----
    float* Ocomb = (float*)&SM[0][0][0][0];   // 128 x 64 f32 = 32 KB (reuse staging LDS)
    if (pr == 1) {
        #pragma unroll
        for (int r = 0; r < 16; r++) {
            int qr = (r & 3) + 8 * (r >> 2) + 4 * hi;
            int rr = rg * 32 + qr;
            Ocomb[rr * 64 + l31] = acc0[r];
            Ocomb[rr * 64 + 32 + l31] = acc1[r];
            if (l31 == 0) clB[rr] = lacc[r];
        }
    }
    __syncthreads();
    if (pr == 0) {
        #pragma unroll
        for (int r = 0; r < 16; r++) {
            int qr = (r & 3) + 8 * (r >> 2) + 4 * hi;
            int rr = rg * 32 + qr;
            float lt2 = lacc[r] + clB[rr];
            float dv = 1.0f / lt2;
            float o0 = acc0[r] + Ocomb[rr * 64 + l31];
            float o1 = acc1[r] + Ocomb[rr * 64 + 32 + l31];
            size_t row = (size_t)(b * T + q0 + rr) * 1024 + h * 64;
            y_bf[row + l31] = f2bf(o0 * dv);
            y_bf[row + 32 + l31] = f2bf(o1 * dv);
        }
    }
}

// ---------- projection GEMM: 128x64 tiles -> 512 blocks (2 blocks/CU), BK=64 2-phase ----------
__launch_bounds__(256, 2)
__global__ void k_gemm_proj(const unsigned short* __restrict__ A,
                            const unsigned short* __restrict__ Bt,
                            float* __restrict__ out, const float* __restrict__ bp) {
    __shared__ unsigned short Asm[2][128][64];   // 2 x 16 KB
    __shared__ unsigned short Bsm[2][64][64];    // 2 x 8 KB
    const int K = 1024, nb = 16;         // M=4096 (32 m-tiles), N=1024 (16 n-tiles)
    int cpx = gridDim.x >> 3;
    int bid = (blockIdx.x & 7) * cpx + (blockIdx.x >> 3);   // T1 remap (512%8==0)
    int n0 = (bid % nb) << 6;            // 64-wide n tiles
    int m0 = (bid / nb) << 7;            // 128-tall m tiles
    int t = threadIdx.x;
    int lane = t & 63, w = t >> 6;
    int wr = w >> 1, wc = w & 1;
    int l15 = lane & 15, lg = lane >> 4;
    int sr = lane >> 3;
    int scol = ((lane & 7) ^ sr) << 3;

    f32x4 acc[4][2];
    #pragma unroll
    for (int i = 0; i < 4; i++)
        #pragma unroll
        for (int j = 0; j < 2; j++) acc[i][j] = (f32x4){0.f, 0.f, 0.f, 0.f};

    auto STAGE = [&](int kt, int buf) {
        #pragma unroll
        for (int q = 0; q < 4; q++) {
            int rb = q * 32 + w * 8;
            gload_lds16(&A[(size_t)(m0 + rb + sr) * K + kt + scol], &Asm[buf][rb][0]);
        }
        #pragma unroll
        for (int q = 0; q < 2; q++) {
            int rb = q * 32 + w * 8;
            gload_lds16(&Bt[(size_t)(n0 + rb + sr) * K + kt + scol], &Bsm[buf][rb][0]);
        }
    };

    const int NT = K >> 6;
    STAGE(0, 0);
    asm volatile("s_waitcnt vmcnt(0)" ::: "memory");
    __builtin_amdgcn_s_barrier();
    int cur = 0;

    for (int tt = 0; tt < NT; tt++) {
        if (tt + 1 < NT) STAGE((tt + 1) << 6, cur ^ 1);
        bf16x8 af[4][2], bfr[2][2];
        int x15 = (l15 & 7) << 3;
        #pragma unroll
        for (int mi = 0; mi < 4; mi++) {
            int row = wr * 64 + mi * 16 + l15;
            af[mi][0] = *reinterpret_cast<const bf16x8*>(&Asm[cur][row][(lg * 8) ^ x15]);
            af[mi][1] = *reinterpret_cast<const bf16x8*>(&Asm[cur][row][(32 + lg * 8) ^ x15]);
        }
        #pragma unroll
        for (int nj = 0; nj < 2; nj++) {
            int row = wc * 32 + nj * 16 + l15;
            bfr[nj][0] = *reinterpret_cast<const bf16x8*>(&Bsm[cur][row][(lg * 8) ^ x15]);
            bfr[nj][1] = *reinterpret_cast<const bf16x8*>(&Bsm[cur][row][(32 + lg * 8) ^ x15]);
        }
        asm volatile("s_waitcnt lgkmcnt(0)" ::: "memory");
        __builtin_amdgcn_sched_barrier(0);
        __builtin_amdgcn_s_setprio(1);
        #pragma unroll
        for (int mi = 0; mi < 4; mi++)
            #pragma unroll
            for (int nj = 0; nj < 2; nj++) {
                acc[mi][nj] = __builtin_amdgcn_mfma_f32_16x16x32_bf16(af[mi][0], bfr[nj][0], acc[mi][nj], 0, 0, 0);
                acc[mi][nj] = __builtin_amdgcn_mfma_f32_16x16x32_bf16(af[mi][1], bfr[nj][1], acc[mi][nj], 0, 0, 0);
            }
        __builtin_amdgcn_s_setprio(0);
        asm volatile("s_waitcnt vmcnt(0)" ::: "memory");
        __builtin_amdgcn_s_barrier();
        cur ^= 1;
    }

    #pragma unroll
    for (int mi = 0; mi < 4; mi++)
        #pragma unroll
        for (int nj = 0; nj < 2; nj++)
            #pragma unroll
            for (int r = 0; r < 4; r++) {
                int m = m0 + wr * 64 + mi * 16 + lg * 4 + r;
                int n = n0 + wc * 32 + nj * 16 + l15;
                out[(size_t)m * 1024 + n] = acc[mi][nj][r] + bp[n];
            }
}

// ---------- launch ----------
extern "C" void kernel_launch(void* const* d_in, const int* in_sizes, int n_in,
                              void* d_out, int out_size, void* d_ws, size_t ws_size,
                              hipStream_t stream) {
    const float* x  = (const float*)d_in[0];
    const float* Wq = (const float*)d_in[1];
    const float* Wk = (const float*)d_in[2];
    const float* Wv = (const float*)d_in[3];
    const float* Wp = (const float*)d_in[4];
    const float* bp = (const float*)d_in[5];
    float* out = (float*)d_out;

    char* ws = (char*)d_ws;
    unsigned short* x_bf  = (unsigned short*)(ws);                           // 8 MB
    unsigned short* Wt    = (unsigned short*)(ws + ((size_t)8  << 20));      // 6 MB
    unsigned short* Wp_bf = (unsigned short*)(ws + ((size_t)14 << 20));      // 2 MB
    unsigned short* q_nat = (unsigned short*)(ws + ((size_t)16 << 20));      // 8 MB
    unsigned short* k_nat = (unsigned short*)(ws + ((size_t)24 << 20));      // 8 MB
    unsigned short* vT    = (unsigned short*)(ws + ((size_t)32 << 20));      // 8 MB
    unsigned short* y_bf  = (unsigned short*)(ws + ((size_t)40 << 20));      // 8 MB

    k_cvt_all<<<5888, 256, 0, stream>>>(x, Wp, Wq, Wk, Wv, x_bf, Wp_bf, Wt);
    k_gemm_qkv<<<768, 256, 0, stream>>>(x_bf, Wt, q_nat, k_nat, vT);
    k_attn<<<512, 512, 0, stream>>>(q_nat, k_nat, vT, y_bf);
    k_gemm_proj<<<512, 256, 0, stream>>>(y_bf, Wp_bf, out, bp);
}